// Round 9
// baseline (99.176 us; speedup 1.0000x reference)
//
#include <hip/hip_runtime.h>
#include <hip/hip_bf16.h>

#define BB 4
#define CC 128
#define NN 4096
#define CK 32
#define L2E 1.442695040888963f

typedef __attribute__((ext_vector_type(8))) short short8v;
typedef __attribute__((ext_vector_type(4))) float float4v;

__device__ inline ushort f2bf(float f) {
    union { __hip_bfloat16 h; ushort u; } cv;
    cv.h = __float2bfloat16(f);
    return cv.u;
}
__device__ inline uint pk2(float lo, float hi) {
    return ((uint)f2bf(lo)) | ((uint)f2bf(hi) << 16);
}
__device__ __forceinline__ void gll16(const void* g, void* l) {
    __builtin_amdgcn_global_load_lds(
        (const __attribute__((address_space(1))) void*)g,
        (__attribute__((address_space(3))) void*)l, 16, 0, 0);
}

// ---------------------------------------------------------------------------
// Kernel 1: projections -> bf16.  ft/gt [b][n][32]; v [b][c][n], sign(gamma)
// folded in.
// ---------------------------------------------------------------------------
__global__ __launch_bounds__(256) void proj_kernel(
    const float* __restrict__ x,
    const float* __restrict__ Wf, const float* __restrict__ bf,
    const float* __restrict__ Wg, const float* __restrict__ bg,
    const float* __restrict__ Wh, const float* __restrict__ bh,
    const float* __restrict__ gamma,
    ushort* __restrict__ ft, ushort* __restrict__ gt, ushort* __restrict__ vh)
{
    __shared__ float xs[CC][64];
    const int t  = threadIdx.x;
    const int n0 = blockIdx.x * 64;
    const int b  = blockIdx.y;
    const float* xb = x + (size_t)b * CC * NN + n0;

    {
        const int j = t & 63;
        #pragma unroll
        for (int i = 0; i < 32; ++i) {
            const int c = (t >> 6) + 4 * i;
            xs[c][j] = xb[(size_t)c * NN + j];
        }
    }
    __syncthreads();

    const int jq = t & 15;
    const int og = t >> 4;

    float acc[12][4];
    #pragma unroll
    for (int i = 0; i < 12; ++i)
        #pragma unroll
        for (int jj = 0; jj < 4; ++jj) acc[i][jj] = 0.f;

    for (int c = 0; c < CC; ++c) {
        const float4 xv = *reinterpret_cast<const float4*>(&xs[c][jq * 4]);
        #pragma unroll
        for (int i = 0; i < 12; ++i) {
            const int o = og + 16 * i;
            float w;
            if (i < 2)       w = Wf[o * CC + c];
            else if (i < 4)  w = Wg[(o - 32) * CC + c];
            else             w = Wh[(o - 64) * CC + c];
            acc[i][0] += w * xv.x;
            acc[i][1] += w * xv.y;
            acc[i][2] += w * xv.z;
            acc[i][3] += w * xv.w;
        }
    }

    const float sgn = (gamma[0] < 0.f) ? -1.f : 1.f;
    const int n_base = n0 + jq * 4;
    #pragma unroll
    for (int i = 0; i < 2; ++i) {
        const int o = og + 16 * i;
        const float bias = bf[o];
        #pragma unroll
        for (int jj = 0; jj < 4; ++jj)
            ft[((size_t)b * NN + n_base + jj) * CK + o] = f2bf(acc[i][jj] + bias);
    }
    #pragma unroll
    for (int i = 2; i < 4; ++i) {
        const int o = og + 16 * (i - 2);
        const float bias = bg[o];
        #pragma unroll
        for (int jj = 0; jj < 4; ++jj)
            gt[((size_t)b * NN + n_base + jj) * CK + o] = f2bf(acc[i][jj] + bias);
    }
    #pragma unroll
    for (int i = 4; i < 12; ++i) {
        const int c = og + 16 * (i - 4);
        const float bias = bh[c];
        ushort4 pkv;
        pkv.x = f2bf(sgn * (acc[i][0] + bias));
        pkv.y = f2bf(sgn * (acc[i][1] + bias));
        pkv.z = f2bf(sgn * (acc[i][2] + bias));
        pkv.w = f2bf(sgn * (acc[i][3] + bias));
        *reinterpret_cast<ushort4*>(&vh[((size_t)b * CC + c) * NN + n_base]) = pkv;
    }
}

// ---------------------------------------------------------------------------
// Kernel 2: partial softmax denominators via MFMA.  Grid (N/64, B, 8 chunks)
// = 2048 blocks = 8 blocks/CU = 8 waves/SIMD (latency-hide the load chain).
// ---------------------------------------------------------------------------
__global__ __launch_bounds__(256) void pass1_kernel(
    const ushort* __restrict__ ft, const ushort* __restrict__ gt,
    float* __restrict__ Dpart)
{
    const int t   = threadIdx.x;
    const int w   = t >> 6;
    const int l   = t & 63;
    const int g16 = l >> 4;
    const int l16 = l & 15;
    const int n0  = blockIdx.x * 64;
    const int b   = blockIdx.y;
    const int mz  = blockIdx.z;

    const ushort* ftb = ft + (size_t)b * NN * CK;
    const ushort* gtb = gt + (size_t)b * NN * CK;

    const short8v afrag = *reinterpret_cast<const short8v*>(
        &ftb[(size_t)(n0 + 16 * w + l16) * CK + 8 * g16]);

    const float4v zf = {0.f, 0.f, 0.f, 0.f};
    float d0 = 0.f, d1 = 0.f, d2 = 0.f, d3 = 0.f;
    const int m0 = mz * 512;

    short8v bfA = *reinterpret_cast<const short8v*>(
        &gtb[(size_t)(m0 + l16) * CK + 8 * g16]);
    #pragma unroll 1
    for (int mt = 0; mt < 32; mt += 2) {
        const short8v bfB = *reinterpret_cast<const short8v*>(
            &gtb[(size_t)(m0 + (mt + 1) * 16 + l16) * CK + 8 * g16]);
        float4v s = __builtin_amdgcn_mfma_f32_16x16x32_bf16(afrag, bfA, zf, 0, 0, 0);
        d0 += __expf(s[0]); d1 += __expf(s[1]); d2 += __expf(s[2]); d3 += __expf(s[3]);
        bfA = *reinterpret_cast<const short8v*>(
            &gtb[(size_t)(m0 + (((mt + 2) & 31)) * 16 + l16) * CK + 8 * g16]);
        float4v s2 = __builtin_amdgcn_mfma_f32_16x16x32_bf16(afrag, bfB, zf, 0, 0, 0);
        d0 += __expf(s2[0]); d1 += __expf(s2[1]); d2 += __expf(s2[2]); d3 += __expf(s2[3]);
    }
    #pragma unroll
    for (int msk = 1; msk <= 8; msk <<= 1) {
        d0 += __shfl_xor(d0, msk);
        d1 += __shfl_xor(d1, msk);
        d2 += __shfl_xor(d2, msk);
        d3 += __shfl_xor(d3, msk);
    }
    if (l16 < 4) {
        const int n = n0 + 16 * w + 4 * g16 + l16;
        const float v = (l16 == 0) ? d0 : (l16 == 1) ? d1 : (l16 == 2) ? d2 : d3;
        Dpart[((size_t)b * NN + n) * 8 + mz] = v;
    }
}

// ---------------------------------------------------------------------------
// Kernel 3: Ld = log2(|gamma| / D)
// ---------------------------------------------------------------------------
__global__ __launch_bounds__(256) void reduce_kernel(
    const float* __restrict__ Dpart, float* __restrict__ Ld,
    const float* __restrict__ gamma)
{
    const int i = blockIdx.x * 256 + threadIdx.x;
    const float4 a4 = *reinterpret_cast<const float4*>(&Dpart[(size_t)i * 8]);
    const float4 b4 = *reinterpret_cast<const float4*>(&Dpart[(size_t)i * 8 + 4]);
    const float D = (a4.x + a4.y + a4.z + a4.w) + (b4.x + b4.y + b4.z + b4.w);
    Ld[i] = log2f(fabsf(gamma[0])) - log2f(D);
}

// ---------------------------------------------------------------------------
// Kernel 4: sigma-permuted PV.  1024-thread blocks (16 waves = 4 waves/SIMD),
// 256 blocks (1/CU).  wave = (ch, nq in 0..7); each wave: 512 n in 16 steps.
// V staged wave-private dbuf LDS via global_load_lds (4 gll16/step, counted
// vmcnt(4), no barriers in loop); af/Ld direct global (TLP hides latency).
// Epilogue: 3-round cross-nq log-reduction reusing the 128KB staging LDS.
// ---------------------------------------------------------------------------
#define BUFB  4096
#define WSTR  8192

__global__ __launch_bounds__(1024, 4) void pass2_kernel(
    const ushort* __restrict__ ft, const ushort* __restrict__ gt,
    const ushort* __restrict__ vh, const float* __restrict__ Ld,
    const float* __restrict__ x, float* __restrict__ out)
{
    __shared__ __align__(16) char smem[16 * WSTR];   // 128 KB

    const int t   = threadIdx.x;
    const int w   = t >> 6;
    const int l   = t & 63;
    const int g16 = l >> 4;
    const int l16 = l & 15;
    const int ch  = w & 1;     // c-half
    const int nq  = w >> 1;    // n-eighth (0..7)

    const int bid = blockIdx.x;
    const int xcd = bid & 7;
    const int b   = xcd >> 1;
    const int m0  = ((bid >> 3) + 32 * (xcd & 1)) * 64;

    const ushort* ftb = ft + (size_t)b * NN * CK;
    const ushort* gtb = gt + (size_t)b * NN * CK;
    const ushort* vhb = vh + (size_t)b * CC * NN;
    const float*  ldb = Ld + (size_t)b * NN;

    char* wsm = smem + w * WSTR;

    short8v gfrag[4];
    #pragma unroll
    for (int tm = 0; tm < 4; ++tm)
        gfrag[tm] = *reinterpret_cast<const short8v*>(
            &gtb[(size_t)(m0 + 16 * tm + l16) * CK + 8 * g16]);

    const float4v zf = {0.f, 0.f, 0.f, 0.f};
    float4v acc[4][4];   // [tc][tm]
    #pragma unroll
    for (int tc = 0; tc < 4; ++tc)
        #pragma unroll
        for (int tm = 0; tm < 4; ++tm) acc[tc][tm] = zf;

    const int nbase = nq * 512;
    const int rr = l >> 2, cp = l & 3;

#define STAGE(n0_, bo_) do {                                                   \
    _Pragma("unroll")                                                          \
    for (int j = 0; j < 4; ++j) {                                              \
        const int row = j * 16 + rr;                                           \
        gll16(vhb + (size_t)(64 * ch + row) * NN + (n0_)                       \
                  + (((2 * cp) ^ (row & 6)) << 2),                             \
              wsm + (bo_) + j * 1024);                                         \
    }                                                                          \
} while (0)

    // prologue: stage step 0, drain (also covers gfrag loads)
    STAGE(nbase, 0);
    asm volatile("s_waitcnt vmcnt(0)" ::: "memory");

    int bo = 0;
    #pragma unroll 1
    for (int st = 0; st < 16; ++st) {
        const int n0 = nbase + st * 32;

        // direct global loads FIRST (so their wait is vmcnt(4), not 0)
        const short8v af0 = *reinterpret_cast<const short8v*>(
            &ftb[(size_t)(n0 + l16) * CK + 8 * g16]);
        const short8v af1 = *reinterpret_cast<const short8v*>(
            &ftb[(size_t)(n0 + 16 + l16) * CK + 8 * g16]);
        const float4 ld0 = *reinterpret_cast<const float4*>(&ldb[n0 + 4 * g16]);
        const float4 ld1 = *reinterpret_cast<const float4*>(&ldb[n0 + 16 + 4 * g16]);

        if (st < 15) {
            STAGE(n0 + 32, bo ^ BUFB);
            asm volatile("s_waitcnt vmcnt(4)" ::: "memory");
        } else {
            asm volatile("s_waitcnt vmcnt(0)" ::: "memory");
        }

        const char* Vb = wsm + bo;

        // S = F^T G; P = exp2(S*log2e + Ld) packed bf16 -> PV B-frag directly
        union { uint u[4]; short8v s; } pf[4];
        #pragma unroll
        for (int tm = 0; tm < 4; ++tm) {
            float4v s0 = __builtin_amdgcn_mfma_f32_16x16x32_bf16(af0, gfrag[tm], zf, 0, 0, 0);
            float4v s1 = __builtin_amdgcn_mfma_f32_16x16x32_bf16(af1, gfrag[tm], zf, 0, 0, 0);
            pf[tm].u[0] = pk2(__builtin_amdgcn_exp2f(fmaf(s0[0], L2E, ld0.x)),
                              __builtin_amdgcn_exp2f(fmaf(s0[1], L2E, ld0.y)));
            pf[tm].u[1] = pk2(__builtin_amdgcn_exp2f(fmaf(s0[2], L2E, ld0.z)),
                              __builtin_amdgcn_exp2f(fmaf(s0[3], L2E, ld0.w)));
            pf[tm].u[2] = pk2(__builtin_amdgcn_exp2f(fmaf(s1[0], L2E, ld1.x)),
                              __builtin_amdgcn_exp2f(fmaf(s1[1], L2E, ld1.y)));
            pf[tm].u[3] = pk2(__builtin_amdgcn_exp2f(fmaf(s1[2], L2E, ld1.z)),
                              __builtin_amdgcn_exp2f(fmaf(s1[3], L2E, ld1.w)));
        }

        // PV: acc[c,m] += V[c, sigma(k)] * P[sigma(k), m]
        #pragma unroll
        for (int tc = 0; tc < 4; ++tc) {
            const int cl = 16 * tc + l16;
            const uint2 va  = *reinterpret_cast<const uint2*>(
                Vb + cl * 64 + 8 * (g16 ^ (cl & 6)));
            const uint2 vb2 = *reinterpret_cast<const uint2*>(
                Vb + cl * 64 + 8 * ((4 + g16) ^ (cl & 6)));
            union { uint u[4]; short8v s; } av;
            av.u[0] = va.x;  av.u[1] = va.y;
            av.u[2] = vb2.x; av.u[3] = vb2.y;
            #pragma unroll
            for (int tm = 0; tm < 4; ++tm)
                acc[tc][tm] = __builtin_amdgcn_mfma_f32_16x16x32_bf16(av.s, pf[tm].s, acc[tc][tm], 0, 0, 0);
        }
        bo ^= BUFB;
    }
#undef STAGE

    // ---- epilogue: 3-round cross-nq reduction (staging LDS reused) ----
    float4v* rl = (float4v*)smem;
    __syncthreads();
    if (nq >= 4) {
        const int slot = (nq - 4) * 2 + ch;
        #pragma unroll
        for (int tc = 0; tc < 4; ++tc)
            #pragma unroll
            for (int tm = 0; tm < 4; ++tm)
                rl[(slot * 16 + tc * 4 + tm) * 64 + l] = acc[tc][tm];
    }
    __syncthreads();
    if (nq < 4) {
        const int slot = nq * 2 + ch;
        #pragma unroll
        for (int tc = 0; tc < 4; ++tc)
            #pragma unroll
            for (int tm = 0; tm < 4; ++tm)
                acc[tc][tm] += rl[(slot * 16 + tc * 4 + tm) * 64 + l];
    }
    __syncthreads();
    if (nq == 2 || nq == 3) {
        const int slot = (nq - 2) * 2 + ch;
        #pragma unroll
        for (int tc = 0; tc < 4; ++tc)
            #pragma unroll
            for (int tm = 0; tm < 4; ++tm)
                rl[(slot * 16 + tc * 4 + tm) * 64 + l] = acc[tc][tm];
    }
    __syncthreads();
    if (nq < 2) {
        const int slot = nq * 2 + ch;
        #pragma unroll
        for (int tc = 0; tc < 4; ++tc)
            #pragma unroll
            for (int tm = 0; tm < 4; ++tm)
                acc[tc][tm] += rl[(slot * 16 + tc * 4 + tm) * 64 + l];
    }
    __syncthreads();
    if (nq == 1) {
        #pragma unroll
        for (int tc = 0; tc < 4; ++tc)
            #pragma unroll
            for (int tm = 0; tm < 4; ++tm)
                rl[(ch * 16 + tc * 4 + tm) * 64 + l] = acc[tc][tm];
    }
    __syncthreads();
    if (nq == 0) {
        const float* xb = x   + (size_t)b * CC * NN;
        float*       ob = out + (size_t)b * CC * NN;
        #pragma unroll
        for (int tc = 0; tc < 4; ++tc) {
            #pragma unroll
            for (int tm = 0; tm < 4; ++tm) {
                float4v s = acc[tc][tm] + rl[(ch * 16 + tc * 4 + tm) * 64 + l];
                const int cb = 64 * ch + 16 * tc + 4 * g16;
                const int m  = m0 + 16 * tm + l16;
                #pragma unroll
                for (int r = 0; r < 4; ++r) {
                    const size_t idx = (size_t)(cb + r) * NN + m;
                    ob[idx] = s[r] + xb[idx];
                }
            }
        }
    }
}

// ---------------------------------------------------------------------------
extern "C" void kernel_launch(void* const* d_in, const int* in_sizes, int n_in,
                              void* d_out, int out_size, void* d_ws, size_t ws_size,
                              hipStream_t stream)
{
    const float* x     = (const float*)d_in[0];
    const float* Wf    = (const float*)d_in[1];
    const float* bf    = (const float*)d_in[2];
    const float* Wg    = (const float*)d_in[3];
    const float* bg    = (const float*)d_in[4];
    const float* Wh    = (const float*)d_in[5];
    const float* bh    = (const float*)d_in[6];
    const float* gamma = (const float*)d_in[7];

    ushort* ft = (ushort*)d_ws;                    // [B][N][CK] bf16
    ushort* gt = ft + (size_t)BB * NN * CK;        // [B][N][CK] bf16
    ushort* vh = gt + (size_t)BB * NN * CK;        // [B][C][N]  bf16 (sign-folded)
    float* Dpart = (float*)(vh + (size_t)BB * CC * NN);  // [B*N][8]
    float* Ld    = Dpart + (size_t)BB * NN * 8;          // [B*N] log2(|g|/D)

    float* out = (float*)d_out;

    proj_kernel<<<dim3(NN / 64, BB), 256, 0, stream>>>(x, Wf, bf, Wg, bg, Wh, bh, gamma, ft, gt, vh);
    pass1_kernel<<<dim3(NN / 64, BB, 8), 256, 0, stream>>>(ft, gt, Dpart);
    reduce_kernel<<<dim3(BB * NN / 256), 256, 0, stream>>>(Dpart, Ld, gamma);
    pass2_kernel<<<dim3(256), 1024, 0, stream>>>(ft, gt, vh, Ld, x, out);
}

// Round 13
// 87.146 us; speedup vs baseline: 1.1380x; 1.1380x over previous
//
#include <hip/hip_runtime.h>
#include <hip/hip_bf16.h>

#define BB 4
#define CC 128
#define NN 4096
#define CK 32
#define L2E 1.442695040888963f

typedef __attribute__((ext_vector_type(8))) short short8v;
typedef __attribute__((ext_vector_type(4))) float float4v;

__device__ inline ushort f2bf(float f) {
    union { __hip_bfloat16 h; ushort u; } cv;
    cv.h = __float2bfloat16(f);
    return cv.u;
}
__device__ inline uint pk2(float lo, float hi) {
    return ((uint)f2bf(lo)) | ((uint)f2bf(hi) << 16);
}
__device__ __forceinline__ void gll16(const void* g, void* l) {
    __builtin_amdgcn_global_load_lds(
        (const __attribute__((address_space(1))) void*)g,
        (__attribute__((address_space(3))) void*)l, 16, 0, 0);
}
__device__ __forceinline__ void gll4(const void* g, void* l) {
    __builtin_amdgcn_global_load_lds(
        (const __attribute__((address_space(1))) void*)g,
        (__attribute__((address_space(3))) void*)l, 4, 0, 0);
}

// ---------------------------------------------------------------------------
// Kernel 1: projections -> bf16.  ft/gt [b][n][32]; v [b][c][n], sign(gamma)
// folded in.  1024 threads (4 waves/SIMD for latency hiding); thread =
// (pixel-quad jq, o-group og, o-slot triple i3).  W loaded as float4.
// ---------------------------------------------------------------------------
__global__ __launch_bounds__(1024) void proj_kernel(
    const float* __restrict__ x,
    const float* __restrict__ Wf, const float* __restrict__ bf,
    const float* __restrict__ Wg, const float* __restrict__ bg,
    const float* __restrict__ Wh, const float* __restrict__ bh,
    const float* __restrict__ gamma,
    ushort* __restrict__ ft, ushort* __restrict__ gt, ushort* __restrict__ vh)
{
    __shared__ float xs[CC][64];
    const int t  = threadIdx.x;
    const int n0 = blockIdx.x * 64;
    const int b  = blockIdx.y;
    const float* xb = x + (size_t)b * CC * NN + n0;

    {
        const int j  = t & 63;
        const int cb = t >> 6;   // 0..15
        #pragma unroll
        for (int i = 0; i < 8; ++i)
            xs[cb + 16 * i][j] = xb[(size_t)(cb + 16 * i) * NN + j];
    }
    __syncthreads();

    const int jq = t & 15;          // pixel quad
    const int og = (t >> 4) & 15;   // output-channel group
    const int i3 = t >> 8;          // o-slot triple (wave-uniform)

    // per-slot setup: W row pointer, bias, destination mode
    const float* wrow[3];
    float biasv[3];
    int   mode[3], oc[3];
    #pragma unroll
    for (int ii = 0; ii < 3; ++ii) {
        const int i = i3 * 3 + ii;
        if (i < 2)      { oc[ii] = og + 16 * i;       wrow[ii] = Wf + oc[ii] * CC; biasv[ii] = bf[oc[ii]]; mode[ii] = 0; }
        else if (i < 4) { oc[ii] = og + 16 * (i - 2); wrow[ii] = Wg + oc[ii] * CC; biasv[ii] = bg[oc[ii]]; mode[ii] = 1; }
        else            { oc[ii] = og + 16 * (i - 4); wrow[ii] = Wh + oc[ii] * CC; biasv[ii] = bh[oc[ii]]; mode[ii] = 2; }
    }

    float acc[3][4];
    #pragma unroll
    for (int ii = 0; ii < 3; ++ii)
        #pragma unroll
        for (int jj = 0; jj < 4; ++jj) acc[ii][jj] = 0.f;

    #pragma unroll 4
    for (int c4 = 0; c4 < 32; ++c4) {
        float4 wv[3];
        #pragma unroll
        for (int ii = 0; ii < 3; ++ii)
            wv[ii] = *reinterpret_cast<const float4*>(&wrow[ii][c4 * 4]);
        #pragma unroll
        for (int q = 0; q < 4; ++q) {
            const float4 xv = *reinterpret_cast<const float4*>(&xs[c4 * 4 + q][jq * 4]);
            #pragma unroll
            for (int ii = 0; ii < 3; ++ii) {
                const float wq = (q == 0) ? wv[ii].x : (q == 1) ? wv[ii].y
                               : (q == 2) ? wv[ii].z : wv[ii].w;
                acc[ii][0] += wq * xv.x;
                acc[ii][1] += wq * xv.y;
                acc[ii][2] += wq * xv.z;
                acc[ii][3] += wq * xv.w;
            }
        }
    }

    const float sgn = (gamma[0] < 0.f) ? -1.f : 1.f;
    const int n_base = n0 + jq * 4;
    #pragma unroll
    for (int ii = 0; ii < 3; ++ii) {
        if (mode[ii] == 0) {
            #pragma unroll
            for (int jj = 0; jj < 4; ++jj)
                ft[((size_t)b * NN + n_base + jj) * CK + oc[ii]] = f2bf(acc[ii][jj] + biasv[ii]);
        } else if (mode[ii] == 1) {
            #pragma unroll
            for (int jj = 0; jj < 4; ++jj)
                gt[((size_t)b * NN + n_base + jj) * CK + oc[ii]] = f2bf(acc[ii][jj] + biasv[ii]);
        } else {
            ushort4 pkv;
            pkv.x = f2bf(sgn * (acc[ii][0] + biasv[ii]));
            pkv.y = f2bf(sgn * (acc[ii][1] + biasv[ii]));
            pkv.z = f2bf(sgn * (acc[ii][2] + biasv[ii]));
            pkv.w = f2bf(sgn * (acc[ii][3] + biasv[ii]));
            *reinterpret_cast<ushort4*>(&vh[((size_t)b * CC + oc[ii]) * NN + n_base]) = pkv;
        }
    }
}

// ---------------------------------------------------------------------------
// Kernel 2: partial softmax denominators via MFMA.  Grid (N/64, B, 8 chunks).
// ---------------------------------------------------------------------------
__global__ __launch_bounds__(256) void pass1_kernel(
    const ushort* __restrict__ ft, const ushort* __restrict__ gt,
    float* __restrict__ Dpart)
{
    const int t   = threadIdx.x;
    const int w   = t >> 6;
    const int l   = t & 63;
    const int g16 = l >> 4;
    const int l16 = l & 15;
    const int n0  = blockIdx.x * 64;
    const int b   = blockIdx.y;
    const int mz  = blockIdx.z;

    const ushort* ftb = ft + (size_t)b * NN * CK;
    const ushort* gtb = gt + (size_t)b * NN * CK;

    const short8v afrag = *reinterpret_cast<const short8v*>(
        &ftb[(size_t)(n0 + 16 * w + l16) * CK + 8 * g16]);

    const float4v zf = {0.f, 0.f, 0.f, 0.f};
    float d0 = 0.f, d1 = 0.f, d2 = 0.f, d3 = 0.f;
    const int m0 = mz * 512;

    short8v bfA = *reinterpret_cast<const short8v*>(
        &gtb[(size_t)(m0 + l16) * CK + 8 * g16]);
    #pragma unroll 1
    for (int mt = 0; mt < 32; mt += 2) {
        const short8v bfB = *reinterpret_cast<const short8v*>(
            &gtb[(size_t)(m0 + (mt + 1) * 16 + l16) * CK + 8 * g16]);
        float4v s = __builtin_amdgcn_mfma_f32_16x16x32_bf16(afrag, bfA, zf, 0, 0, 0);
        d0 += __expf(s[0]); d1 += __expf(s[1]); d2 += __expf(s[2]); d3 += __expf(s[3]);
        bfA = *reinterpret_cast<const short8v*>(
            &gtb[(size_t)(m0 + (((mt + 2) & 31)) * 16 + l16) * CK + 8 * g16]);
        float4v s2 = __builtin_amdgcn_mfma_f32_16x16x32_bf16(afrag, bfB, zf, 0, 0, 0);
        d0 += __expf(s2[0]); d1 += __expf(s2[1]); d2 += __expf(s2[2]); d3 += __expf(s2[3]);
    }
    #pragma unroll
    for (int msk = 1; msk <= 8; msk <<= 1) {
        d0 += __shfl_xor(d0, msk);
        d1 += __shfl_xor(d1, msk);
        d2 += __shfl_xor(d2, msk);
        d3 += __shfl_xor(d3, msk);
    }
    if (l16 < 4) {
        const int n = n0 + 16 * w + 4 * g16 + l16;
        const float v = (l16 == 0) ? d0 : (l16 == 1) ? d1 : (l16 == 2) ? d2 : d3;
        Dpart[((size_t)b * NN + n) * 8 + mz] = v;
    }
}

// ---------------------------------------------------------------------------
// Kernel 3: Ld = log2(|gamma| / D)
// ---------------------------------------------------------------------------
__global__ __launch_bounds__(256) void reduce_kernel(
    const float* __restrict__ Dpart, float* __restrict__ Ld,
    const float* __restrict__ gamma)
{
    const int i = blockIdx.x * 256 + threadIdx.x;
    const float4 a4 = *reinterpret_cast<const float4*>(&Dpart[(size_t)i * 8]);
    const float4 b4 = *reinterpret_cast<const float4*>(&Dpart[(size_t)i * 8 + 4]);
    const float D = (a4.x + a4.y + a4.z + a4.w) + (b4.x + b4.y + b4.z + b4.w);
    Ld[i] = log2f(fabsf(gamma[0])) - log2f(D);
}

// ---------------------------------------------------------------------------
// Kernel 4 (round-8 PROVEN version): sigma-permuted PV with WAVE-PRIVATE
// double-buffered LDS staging via global_load_lds (V 4KB + F 2KB + Ld 256B
// per 32-n step; 7 gll instrs), counted s_waitcnt vmcnt(7), ZERO barriers in
// the main loop.  V stored with even-XOR chunk swizzle -> <=2-way conflicts.
// 256 blocks (1/CU), 8 waves = (ch, nq).  Epilogue reuses staging LDS.
// ---------------------------------------------------------------------------
#define V_OFF 0
#define F_OFF 4096
#define L_OFF 6144
#define BUFB  6400
#define WSTR  12800

__global__ __launch_bounds__(512) void pass2_kernel(
    const ushort* __restrict__ ft, const ushort* __restrict__ gt,
    const ushort* __restrict__ vh, const float* __restrict__ Ld,
    const float* __restrict__ x, float* __restrict__ out)
{
    __shared__ __align__(16) char smem[8 * WSTR];   // 100 KB

    const int t   = threadIdx.x;
    const int w   = t >> 6;
    const int l   = t & 63;
    const int g16 = l >> 4;
    const int l16 = l & 15;
    const int ch  = w & 1;     // c-half
    const int nq  = w >> 1;    // n-quarter

    const int bid = blockIdx.x;
    const int xcd = bid & 7;
    const int b   = xcd >> 1;
    const int m0  = ((bid >> 3) + 32 * (xcd & 1)) * 64;

    const ushort* ftb = ft + (size_t)b * NN * CK;
    const ushort* gtb = gt + (size_t)b * NN * CK;
    const ushort* vhb = vh + (size_t)b * CC * NN;
    const float*  ldb = Ld + (size_t)b * NN;

    char* wsm = smem + w * WSTR;

    short8v gfrag[4];
    #pragma unroll
    for (int tm = 0; tm < 4; ++tm)
        gfrag[tm] = *reinterpret_cast<const short8v*>(
            &gtb[(size_t)(m0 + 16 * tm + l16) * CK + 8 * g16]);

    const float4v zf = {0.f, 0.f, 0.f, 0.f};
    float4v acc[4][4];   // [tc][tm]
    #pragma unroll
    for (int tc = 0; tc < 4; ++tc)
        #pragma unroll
        for (int tm = 0; tm < 4; ++tm) acc[tc][tm] = zf;

    const int nbase = nq * 1024;
    const int rr = l >> 2, cp = l & 3;

#define STAGE(n0_, bo_) do {                                                   \
    _Pragma("unroll")                                                          \
    for (int j = 0; j < 4; ++j) {                                              \
        const int row = j * 16 + rr;                                           \
        gll16(vhb + (size_t)(64 * ch + row) * NN + (n0_)                       \
                  + (((2 * cp) ^ (row & 6)) << 2),                             \
              wsm + (bo_) + V_OFF + j * 1024);                                 \
    }                                                                          \
    _Pragma("unroll")                                                          \
    for (int j = 0; j < 2; ++j) {                                              \
        const int row = j * 16 + rr;                                           \
        gll16(ftb + (size_t)((n0_) + row) * CK + cp * 8,                       \
              wsm + (bo_) + F_OFF + j * 1024);                                 \
    }                                                                          \
    gll4(ldb + (n0_) + (l & 31), wsm + (bo_) + L_OFF);                         \
} while (0)

    // prologue: stage step 0, drain everything (incl. gfrag loads)
    STAGE(nbase, 0);
    asm volatile("s_waitcnt vmcnt(0)" ::: "memory");

    int bo = 0;
    #pragma unroll 1
    for (int st = 0; st < 32; ++st) {
        const int n0 = nbase + st * 32;
        if (st < 31) {
            STAGE(n0 + 32, bo ^ BUFB);
            asm volatile("s_waitcnt vmcnt(7)" ::: "memory");
        } else {
            asm volatile("s_waitcnt vmcnt(0)" ::: "memory");
        }

        const char*  Vb = wsm + bo + V_OFF;
        const char*  Fb = wsm + bo + F_OFF;
        const float* Lb = (const float*)(wsm + bo + L_OFF);

        const short8v af0 = *reinterpret_cast<const short8v*>(Fb + l16 * 64 + g16 * 16);
        const short8v af1 = *reinterpret_cast<const short8v*>(Fb + (16 + l16) * 64 + g16 * 16);
        const float4  ld0 = *reinterpret_cast<const float4*>(Lb + 4 * g16);
        const float4  ld1 = *reinterpret_cast<const float4*>(Lb + 16 + 4 * g16);

        // S = F^T G; P = exp2(S*log2e + Ld) packed bf16 -> PV B-frag directly
        union { uint u[4]; short8v s; } pf[4];
        #pragma unroll
        for (int tm = 0; tm < 4; ++tm) {
            float4v s0 = __builtin_amdgcn_mfma_f32_16x16x32_bf16(af0, gfrag[tm], zf, 0, 0, 0);
            float4v s1 = __builtin_amdgcn_mfma_f32_16x16x32_bf16(af1, gfrag[tm], zf, 0, 0, 0);
            pf[tm].u[0] = pk2(__builtin_amdgcn_exp2f(fmaf(s0[0], L2E, ld0.x)),
                              __builtin_amdgcn_exp2f(fmaf(s0[1], L2E, ld0.y)));
            pf[tm].u[1] = pk2(__builtin_amdgcn_exp2f(fmaf(s0[2], L2E, ld0.z)),
                              __builtin_amdgcn_exp2f(fmaf(s0[3], L2E, ld0.w)));
            pf[tm].u[2] = pk2(__builtin_amdgcn_exp2f(fmaf(s1[0], L2E, ld1.x)),
                              __builtin_amdgcn_exp2f(fmaf(s1[1], L2E, ld1.y)));
            pf[tm].u[3] = pk2(__builtin_amdgcn_exp2f(fmaf(s1[2], L2E, ld1.z)),
                              __builtin_amdgcn_exp2f(fmaf(s1[3], L2E, ld1.w)));
        }

        // PV: acc[c,m] += V[c, sigma(k)] * P[sigma(k), m]
        #pragma unroll
        for (int tc = 0; tc < 4; ++tc) {
            const int cl = 16 * tc + l16;
            const uint2 va = *reinterpret_cast<const uint2*>(
                Vb + cl * 64 + 8 * (g16 ^ (cl & 6)));
            const uint2 vb2 = *reinterpret_cast<const uint2*>(
                Vb + cl * 64 + 8 * ((4 + g16) ^ (cl & 6)));
            union { uint u[4]; short8v s; } av;
            av.u[0] = va.x;  av.u[1] = va.y;
            av.u[2] = vb2.x; av.u[3] = vb2.y;
            #pragma unroll
            for (int tm = 0; tm < 4; ++tm)
                acc[tc][tm] = __builtin_amdgcn_mfma_f32_16x16x32_bf16(av.s, pf[tm].s, acc[tc][tm], 0, 0, 0);
        }
        bo ^= BUFB;
    }
#undef STAGE

    // ---- epilogue: cross-nq reduction (staging LDS reused) ----
    __syncthreads();   // everyone done with private staging regions
    float4v* rl = (float4v*)smem;   // [6][16][64]
    if (nq != 0) {
        const int slot = (nq - 1) * 2 + ch;
        #pragma unroll
        for (int tc = 0; tc < 4; ++tc)
            #pragma unroll
            for (int tm = 0; tm < 4; ++tm)
                rl[(slot * 16 + tc * 4 + tm) * 64 + l] = acc[tc][tm];
    }
    __syncthreads();
    if (nq == 0) {
        const float* xb = x   + (size_t)b * CC * NN;
        float*       ob = out + (size_t)b * CC * NN;
        #pragma unroll
        for (int tc = 0; tc < 4; ++tc) {
            #pragma unroll
            for (int tm = 0; tm < 4; ++tm) {
                const int fi = tc * 4 + tm;
                float4v s = acc[tc][tm]
                          + rl[((ch) * 16 + fi) * 64 + l]
                          + rl[((2 + ch) * 16 + fi) * 64 + l]
                          + rl[((4 + ch) * 16 + fi) * 64 + l];
                const int cb = 64 * ch + 16 * tc + 4 * g16;
                const int m  = m0 + 16 * tm + l16;
                #pragma unroll
                for (int r = 0; r < 4; ++r) {
                    const size_t idx = (size_t)(cb + r) * NN + m;
                    ob[idx] = s[r] + xb[idx];
                }
            }
        }
    }
}

// ---------------------------------------------------------------------------
extern "C" void kernel_launch(void* const* d_in, const int* in_sizes, int n_in,
                              void* d_out, int out_size, void* d_ws, size_t ws_size,
                              hipStream_t stream)
{
    const float* x     = (const float*)d_in[0];
    const float* Wf    = (const float*)d_in[1];
    const float* bf    = (const float*)d_in[2];
    const float* Wg    = (const float*)d_in[3];
    const float* bg    = (const float*)d_in[4];
    const float* Wh    = (const float*)d_in[5];
    const float* bh    = (const float*)d_in[6];
    const float* gamma = (const float*)d_in[7];

    ushort* ft = (ushort*)d_ws;                    // [B][N][CK] bf16
    ushort* gt = ft + (size_t)BB * NN * CK;        // [B][N][CK] bf16
    ushort* vh = gt + (size_t)BB * NN * CK;        // [B][C][N]  bf16 (sign-folded)
    float* Dpart = (float*)(vh + (size_t)BB * CC * NN);  // [B*N][8]
    float* Ld    = Dpart + (size_t)BB * NN * 8;          // [B*N] log2(|g|/D)

    float* out = (float*)d_out;

    proj_kernel<<<dim3(NN / 64, BB), 1024, 0, stream>>>(x, Wf, bf, Wg, bg, Wh, bh, gamma, ft, gt, vh);
    pass1_kernel<<<dim3(NN / 64, BB, 8), 256, 0, stream>>>(ft, gt, Dpart);
    reduce_kernel<<<dim3(BB * NN / 256), 256, 0, stream>>>(Dpart, Ld, gamma);
    pass2_kernel<<<dim3(256), 512, 0, stream>>>(ft, gt, vh, Ld, x, out);
}

// Round 14
// 83.527 us; speedup vs baseline: 1.1874x; 1.0433x over previous
//
#include <hip/hip_runtime.h>
#include <hip/hip_bf16.h>

#define BB 4
#define CC 128
#define NN 4096
#define CK 32
#define L2E 1.442695040888963f

typedef __attribute__((ext_vector_type(8))) short short8v;
typedef __attribute__((ext_vector_type(4))) float float4v;

__device__ inline ushort f2bf(float f) {
    union { __hip_bfloat16 h; ushort u; } cv;
    cv.h = __float2bfloat16(f);
    return cv.u;
}
__device__ inline float bf2f(ushort u) {
    union { uint u; float f; } cv;
    cv.u = ((uint)u) << 16;
    return cv.f;
}
__device__ inline uint pk2(float lo, float hi) {
    return ((uint)f2bf(lo)) | ((uint)f2bf(hi) << 16);
}
__device__ __forceinline__ void gll16(const void* g, void* l) {
    __builtin_amdgcn_global_load_lds(
        (const __attribute__((address_space(1))) void*)g,
        (__attribute__((address_space(3))) void*)l, 16, 0, 0);
}

// ---------------------------------------------------------------------------
// Kernel 1: projections -> bf16.  ft = (Wf x + bf) * log2e  [b][n][32];
// gt [b][n][32]; v [b][c][n] with sign(gamma) folded in.
// ---------------------------------------------------------------------------
__global__ __launch_bounds__(1024) void proj_kernel(
    const float* __restrict__ x,
    const float* __restrict__ Wf, const float* __restrict__ bf,
    const float* __restrict__ Wg, const float* __restrict__ bg,
    const float* __restrict__ Wh, const float* __restrict__ bh,
    const float* __restrict__ gamma,
    ushort* __restrict__ ft, ushort* __restrict__ gt, ushort* __restrict__ vh)
{
    __shared__ float xs[CC][64];
    const int t  = threadIdx.x;
    const int n0 = blockIdx.x * 64;
    const int b  = blockIdx.y;
    const float* xb = x + (size_t)b * CC * NN + n0;

    {
        const int j  = t & 63;
        const int cb = t >> 6;   // 0..15
        #pragma unroll
        for (int i = 0; i < 8; ++i)
            xs[cb + 16 * i][j] = xb[(size_t)(cb + 16 * i) * NN + j];
    }
    __syncthreads();

    const int jq = t & 15;          // pixel quad
    const int og = (t >> 4) & 15;   // output-channel group
    const int i3 = t >> 8;          // o-slot triple (wave-uniform)

    const float* wrow[3];
    float biasv[3];
    int   mode[3], oc[3];
    #pragma unroll
    for (int ii = 0; ii < 3; ++ii) {
        const int i = i3 * 3 + ii;
        if (i < 2)      { oc[ii] = og + 16 * i;       wrow[ii] = Wf + oc[ii] * CC; biasv[ii] = bf[oc[ii]]; mode[ii] = 0; }
        else if (i < 4) { oc[ii] = og + 16 * (i - 2); wrow[ii] = Wg + oc[ii] * CC; biasv[ii] = bg[oc[ii]]; mode[ii] = 1; }
        else            { oc[ii] = og + 16 * (i - 4); wrow[ii] = Wh + oc[ii] * CC; biasv[ii] = bh[oc[ii]]; mode[ii] = 2; }
    }

    float acc[3][4];
    #pragma unroll
    for (int ii = 0; ii < 3; ++ii)
        #pragma unroll
        for (int jj = 0; jj < 4; ++jj) acc[ii][jj] = 0.f;

    #pragma unroll 4
    for (int c4 = 0; c4 < 32; ++c4) {
        float4 wv[3];
        #pragma unroll
        for (int ii = 0; ii < 3; ++ii)
            wv[ii] = *reinterpret_cast<const float4*>(&wrow[ii][c4 * 4]);
        #pragma unroll
        for (int q = 0; q < 4; ++q) {
            const float4 xv = *reinterpret_cast<const float4*>(&xs[c4 * 4 + q][jq * 4]);
            #pragma unroll
            for (int ii = 0; ii < 3; ++ii) {
                const float wq = (q == 0) ? wv[ii].x : (q == 1) ? wv[ii].y
                               : (q == 2) ? wv[ii].z : wv[ii].w;
                acc[ii][0] += wq * xv.x;
                acc[ii][1] += wq * xv.y;
                acc[ii][2] += wq * xv.z;
                acc[ii][3] += wq * xv.w;
            }
        }
    }

    const float sgn = (gamma[0] < 0.f) ? -1.f : 1.f;
    const int n_base = n0 + jq * 4;
    #pragma unroll
    for (int ii = 0; ii < 3; ++ii) {
        if (mode[ii] == 0) {
            #pragma unroll
            for (int jj = 0; jj < 4; ++jj)
                ft[((size_t)b * NN + n_base + jj) * CK + oc[ii]] =
                    f2bf((acc[ii][jj] + biasv[ii]) * L2E);
        } else if (mode[ii] == 1) {
            #pragma unroll
            for (int jj = 0; jj < 4; ++jj)
                gt[((size_t)b * NN + n_base + jj) * CK + oc[ii]] = f2bf(acc[ii][jj] + biasv[ii]);
        } else {
            ushort4 pkv;
            pkv.x = f2bf(sgn * (acc[ii][0] + biasv[ii]));
            pkv.y = f2bf(sgn * (acc[ii][1] + biasv[ii]));
            pkv.z = f2bf(sgn * (acc[ii][2] + biasv[ii]));
            pkv.w = f2bf(sgn * (acc[ii][3] + biasv[ii]));
            *reinterpret_cast<ushort4*>(&vh[((size_t)b * CC + oc[ii]) * NN + n_base]) = pkv;
        }
    }
}

// ---------------------------------------------------------------------------
// Kernel 2: partial denominators D = sum_m 2^(S~) via MFMA (S~ carries log2e).
// ---------------------------------------------------------------------------
__global__ __launch_bounds__(256) void pass1_kernel(
    const ushort* __restrict__ ft, const ushort* __restrict__ gt,
    float* __restrict__ Dpart)
{
    const int t   = threadIdx.x;
    const int w   = t >> 6;
    const int l   = t & 63;
    const int g16 = l >> 4;
    const int l16 = l & 15;
    const int n0  = blockIdx.x * 64;
    const int b   = blockIdx.y;
    const int mz  = blockIdx.z;

    const ushort* ftb = ft + (size_t)b * NN * CK;
    const ushort* gtb = gt + (size_t)b * NN * CK;

    const short8v afrag = *reinterpret_cast<const short8v*>(
        &ftb[(size_t)(n0 + 16 * w + l16) * CK + 8 * g16]);

    const float4v zf = {0.f, 0.f, 0.f, 0.f};
    float d0 = 0.f, d1 = 0.f, d2 = 0.f, d3 = 0.f;
    const int m0 = mz * 512;

    short8v bfA = *reinterpret_cast<const short8v*>(
        &gtb[(size_t)(m0 + l16) * CK + 8 * g16]);
    #pragma unroll 1
    for (int mt = 0; mt < 32; mt += 2) {
        const short8v bfB = *reinterpret_cast<const short8v*>(
            &gtb[(size_t)(m0 + (mt + 1) * 16 + l16) * CK + 8 * g16]);
        float4v s = __builtin_amdgcn_mfma_f32_16x16x32_bf16(afrag, bfA, zf, 0, 0, 0);
        d0 += __builtin_amdgcn_exp2f(s[0]); d1 += __builtin_amdgcn_exp2f(s[1]);
        d2 += __builtin_amdgcn_exp2f(s[2]); d3 += __builtin_amdgcn_exp2f(s[3]);
        bfA = *reinterpret_cast<const short8v*>(
            &gtb[(size_t)(m0 + (((mt + 2) & 31)) * 16 + l16) * CK + 8 * g16]);
        float4v s2 = __builtin_amdgcn_mfma_f32_16x16x32_bf16(afrag, bfB, zf, 0, 0, 0);
        d0 += __builtin_amdgcn_exp2f(s2[0]); d1 += __builtin_amdgcn_exp2f(s2[1]);
        d2 += __builtin_amdgcn_exp2f(s2[2]); d3 += __builtin_amdgcn_exp2f(s2[3]);
    }
    #pragma unroll
    for (int msk = 1; msk <= 8; msk <<= 1) {
        d0 += __shfl_xor(d0, msk);
        d1 += __shfl_xor(d1, msk);
        d2 += __shfl_xor(d2, msk);
        d3 += __shfl_xor(d3, msk);
    }
    if (l16 < 4) {
        const int n = n0 + 16 * w + 4 * g16 + l16;
        const float v = (l16 == 0) ? d0 : (l16 == 1) ? d1 : (l16 == 2) ? d2 : d3;
        Dpart[((size_t)b * NN + n) * 8 + mz] = v;
    }
}

// ---------------------------------------------------------------------------
// Kernel 3: sc[n] = |gamma| / D[n]   (softmax scale, folded into V by vscale)
// ---------------------------------------------------------------------------
__global__ __launch_bounds__(256) void reduce_kernel(
    const float* __restrict__ Dpart, float* __restrict__ sc,
    const float* __restrict__ gamma)
{
    const int i = blockIdx.x * 256 + threadIdx.x;
    const float4 a4 = *reinterpret_cast<const float4*>(&Dpart[(size_t)i * 8]);
    const float4 b4 = *reinterpret_cast<const float4*>(&Dpart[(size_t)i * 8 + 4]);
    const float D = (a4.x + a4.y + a4.z + a4.w) + (b4.x + b4.y + b4.z + b4.w);
    sc[i] = fabsf(gamma[0]) / D;
}

// ---------------------------------------------------------------------------
// Kernel 3b: vh[b][c][n] *= sc[b*N + n]   (in place, 8 elems/thread)
// ---------------------------------------------------------------------------
__global__ __launch_bounds__(256) void vscale_kernel(
    ushort* __restrict__ vh, const float* __restrict__ sc)
{
    const size_t i8   = (size_t)blockIdx.x * 256 + threadIdx.x;
    const size_t base = i8 * 8;
    const int    n    = (int)(base & (NN - 1));
    const int    b    = (int)(base / ((size_t)CC * NN));

    ushort4 v0 = *reinterpret_cast<const ushort4*>(&vh[base]);
    ushort4 v1 = *reinterpret_cast<const ushort4*>(&vh[base + 4]);
    const float4 s0 = *reinterpret_cast<const float4*>(&sc[(size_t)b * NN + n]);
    const float4 s1 = *reinterpret_cast<const float4*>(&sc[(size_t)b * NN + n + 4]);

    v0.x = f2bf(bf2f(v0.x) * s0.x);
    v0.y = f2bf(bf2f(v0.y) * s0.y);
    v0.z = f2bf(bf2f(v0.z) * s0.z);
    v0.w = f2bf(bf2f(v0.w) * s0.w);
    v1.x = f2bf(bf2f(v1.x) * s1.x);
    v1.y = f2bf(bf2f(v1.y) * s1.y);
    v1.z = f2bf(bf2f(v1.z) * s1.z);
    v1.w = f2bf(bf2f(v1.w) * s1.w);

    *reinterpret_cast<ushort4*>(&vh[base])     = v0;
    *reinterpret_cast<ushort4*>(&vh[base + 4]) = v1;
}

// ---------------------------------------------------------------------------
// Kernel 4: sigma-permuted PV, wave = (mq in 2, nq in 4) -- each wave owns a
// DISTINCT 32-m x 2048-n rectangle: S/exp/pack computed exactly once
// block-wide.  P = exp2(S~) directly (scales folded into ft and vh).
// V [128c][32n] wave-private dbuf LDS via 8 x gll16/step, counted vmcnt(8),
// af0/af1 direct global loads issued BEFORE the glls (round-9-proven mix),
// ZERO barriers in the main loop.  256 blocks (1/CU), 512 thr, 128 KB LDS.
// ---------------------------------------------------------------------------
#define WSTR  16384
#define VBUF  8192

__global__ __launch_bounds__(512) void pass2_kernel(
    const ushort* __restrict__ ft, const ushort* __restrict__ gt,
    const ushort* __restrict__ vh,
    const float* __restrict__ x, float* __restrict__ out)
{
    __shared__ __align__(16) char smem[8 * WSTR];   // 128 KB

    const int t   = threadIdx.x;
    const int w   = t >> 6;
    const int l   = t & 63;
    const int g16 = l >> 4;
    const int l16 = l & 15;
    const int mq  = w & 1;     // m-half of the 64-m tile
    const int nq  = w >> 1;    // n-quarter

    const int bid = blockIdx.x;
    const int xcd = bid & 7;
    const int b   = xcd >> 1;
    const int m0  = ((bid >> 3) + 32 * (xcd & 1)) * 64;

    const ushort* ftb = ft + (size_t)b * NN * CK;
    const ushort* gtb = gt + (size_t)b * NN * CK;
    const ushort* vhb = vh + (size_t)b * CC * NN;

    char* wsm = smem + w * WSTR;

    short8v gfrag[2];
    #pragma unroll
    for (int tm = 0; tm < 2; ++tm)
        gfrag[tm] = *reinterpret_cast<const short8v*>(
            &gtb[(size_t)(m0 + 32 * mq + 16 * tm + l16) * CK + 8 * g16]);

    const float4v zf = {0.f, 0.f, 0.f, 0.f};
    float4v acc[8][2];   // [tc][tm]
    #pragma unroll
    for (int tc = 0; tc < 8; ++tc)
        #pragma unroll
        for (int tm = 0; tm < 2; ++tm) acc[tc][tm] = zf;

    const int nbase = nq * 1024;
    const int rr = l >> 2, cp = l & 3;

#define STAGE(n0_, bo_) do {                                                   \
    _Pragma("unroll")                                                          \
    for (int j = 0; j < 8; ++j) {                                              \
        const int row = j * 16 + rr;                                           \
        gll16(vhb + (size_t)row * NN + (n0_)                                   \
                  + (((2 * cp) ^ (row & 6)) << 2),                             \
              wsm + (bo_) + j * 1024);                                         \
    }                                                                          \
} while (0)

    // prologue: stage step 0, drain (also covers gfrag loads)
    STAGE(nbase, 0);
    asm volatile("s_waitcnt vmcnt(0)" ::: "memory");

    int bo = 0;
    #pragma unroll 1
    for (int st = 0; st < 32; ++st) {
        const int n0 = nbase + st * 32;

        // direct global af loads FIRST (so staging wait doesn't cover them)
        const short8v af0 = *reinterpret_cast<const short8v*>(
            &ftb[(size_t)(n0 + l16) * CK + 8 * g16]);
        const short8v af1 = *reinterpret_cast<const short8v*>(
            &ftb[(size_t)(n0 + 16 + l16) * CK + 8 * g16]);

        if (st < 31) {
            STAGE(n0 + 32, bo ^ VBUF);
            asm volatile("s_waitcnt vmcnt(8)" ::: "memory");
        } else {
            asm volatile("s_waitcnt vmcnt(0)" ::: "memory");
        }

        const char* Vb = wsm + bo;

        // S~ = (F*log2e)^T G; P = exp2(S~) packed bf16 -> PV B-frag directly
        union { uint u[4]; short8v s; } pf[2];
        #pragma unroll
        for (int tm = 0; tm < 2; ++tm) {
            float4v s0 = __builtin_amdgcn_mfma_f32_16x16x32_bf16(af0, gfrag[tm], zf, 0, 0, 0);
            float4v s1 = __builtin_amdgcn_mfma_f32_16x16x32_bf16(af1, gfrag[tm], zf, 0, 0, 0);
            pf[tm].u[0] = pk2(__builtin_amdgcn_exp2f(s0[0]), __builtin_amdgcn_exp2f(s0[1]));
            pf[tm].u[1] = pk2(__builtin_amdgcn_exp2f(s0[2]), __builtin_amdgcn_exp2f(s0[3]));
            pf[tm].u[2] = pk2(__builtin_amdgcn_exp2f(s1[0]), __builtin_amdgcn_exp2f(s1[1]));
            pf[tm].u[3] = pk2(__builtin_amdgcn_exp2f(s1[2]), __builtin_amdgcn_exp2f(s1[3]));
        }

        // PV: acc[c,m] += V[c, sigma(k)] * P[sigma(k), m]
        #pragma unroll
        for (int tc = 0; tc < 8; ++tc) {
            const int cl = 16 * tc + l16;
            const uint2 va  = *reinterpret_cast<const uint2*>(
                Vb + cl * 64 + 8 * (g16 ^ (cl & 6)));
            const uint2 vb2 = *reinterpret_cast<const uint2*>(
                Vb + cl * 64 + 8 * ((4 + g16) ^ (cl & 6)));
            union { uint u[4]; short8v s; } av;
            av.u[0] = va.x;  av.u[1] = va.y;
            av.u[2] = vb2.x; av.u[3] = vb2.y;
            acc[tc][0] = __builtin_amdgcn_mfma_f32_16x16x32_bf16(av.s, pf[0].s, acc[tc][0], 0, 0, 0);
            acc[tc][1] = __builtin_amdgcn_mfma_f32_16x16x32_bf16(av.s, pf[1].s, acc[tc][1], 0, 0, 0);
        }
        bo ^= VBUF;
    }
#undef STAGE

    // ---- epilogue: cross-nq reduction (staging LDS reused; 96 KB) ----
    __syncthreads();   // everyone done with private staging regions
    float4v* rl = (float4v*)smem;
    if (nq != 0) {
        const int slot = (nq - 1) * 2 + mq;
        #pragma unroll
        for (int tc = 0; tc < 8; ++tc)
            #pragma unroll
            for (int tm = 0; tm < 2; ++tm)
                rl[(slot * 16 + tc * 2 + tm) * 64 + l] = acc[tc][tm];
    }
    __syncthreads();
    if (nq == 0) {
        const float* xb = x   + (size_t)b * CC * NN;
        float*       ob = out + (size_t)b * CC * NN;
        #pragma unroll
        for (int tc = 0; tc < 8; ++tc) {
            #pragma unroll
            for (int tm = 0; tm < 2; ++tm) {
                const int fi = tc * 2 + tm;
                float4v s = acc[tc][tm]
                          + rl[((mq) * 16 + fi) * 64 + l]
                          + rl[((2 + mq) * 16 + fi) * 64 + l]
                          + rl[((4 + mq) * 16 + fi) * 64 + l];
                const int cb = 16 * tc + 4 * g16;
                const int m  = m0 + 32 * mq + 16 * tm + l16;
                #pragma unroll
                for (int r = 0; r < 4; ++r) {
                    const size_t idx = (size_t)(cb + r) * NN + m;
                    ob[idx] = s[r] + xb[idx];
                }
            }
        }
    }
}

// ---------------------------------------------------------------------------
extern "C" void kernel_launch(void* const* d_in, const int* in_sizes, int n_in,
                              void* d_out, int out_size, void* d_ws, size_t ws_size,
                              hipStream_t stream)
{
    const float* x     = (const float*)d_in[0];
    const float* Wf    = (const float*)d_in[1];
    const float* bf    = (const float*)d_in[2];
    const float* Wg    = (const float*)d_in[3];
    const float* bg    = (const float*)d_in[4];
    const float* Wh    = (const float*)d_in[5];
    const float* bh    = (const float*)d_in[6];
    const float* gamma = (const float*)d_in[7];

    ushort* ft = (ushort*)d_ws;                    // [B][N][CK] bf16 (x log2e)
    ushort* gt = ft + (size_t)BB * NN * CK;        // [B][N][CK] bf16
    ushort* vh = gt + (size_t)BB * NN * CK;        // [B][C][N]  bf16 (sign+scale folded)
    float* Dpart = (float*)(vh + (size_t)BB * CC * NN);  // [B*N][8]
    float* sc    = Dpart + (size_t)BB * NN * 8;          // [B*N] |g|/D

    float* out = (float*)d_out;

    proj_kernel<<<dim3(NN / 64, BB), 1024, 0, stream>>>(x, Wf, bf, Wg, bg, Wh, bh, gamma, ft, gt, vh);
    pass1_kernel<<<dim3(NN / 64, BB, 8), 256, 0, stream>>>(ft, gt, Dpart);
    reduce_kernel<<<dim3(BB * NN / 256), 256, 0, stream>>>(Dpart, sc, gamma);
    vscale_kernel<<<dim3(BB * CC * NN / 8 / 256), 256, 0, stream>>>(vh, sc);
    pass2_kernel<<<dim3(256), 512, 0, stream>>>(ft, gt, vh, x, out);
}